// Round 1
// baseline (537.932 us; speedup 1.0000x reference)
//
#include <hip/hip_runtime.h>
#include <hip/hip_bf16.h>

typedef __bf16 bf16;
typedef __bf16 bf16x8 __attribute__((ext_vector_type(8)));
typedef float  f32x4  __attribute__((ext_vector_type(4)));

// ---------------------------------------------------------------------------
// Layer-agnostic structure:
//   he[e][j]   = relu(W_a[j]*ea[e] + b_a[j])                       (16 values)
//   We[e][i][o]= sum_j he[j] * W_b[(i*16+o)][j] + b_b[i*16+o]
//   msg[e][o]  = sum_i x[src][i]*We[e][i][o]
//              = sum_k Z[e][k]*W'[k][o]  +  d[src][o]
//     where Z[e][(j,i)] = he[j]*x_src[i],  W'[(j,i)][o] = W_b[(i*16+o)][j],
//           d[v][o] = sum_i x[v][i]*b_b[i*16+o]      (per-node precompute)
//   agg[v] = sum_{e:dst=v} msg[e] / max(cnt[v],1)
//   h[v]   = relu(agg[v] + x[v]@root + bias)
// ---------------------------------------------------------------------------

// Per-node precompute for layer 1: d1 = x@b_e1b', r1 = x@root1 + bias1
__global__ void node_pre1(const float* __restrict__ x,
                          const float* __restrict__ b_e1b,
                          const float* __restrict__ root1,
                          const float* __restrict__ bias1,
                          float* __restrict__ d1, float* __restrict__ r1, int N)
{
    int t = blockIdx.x * blockDim.x + threadIdx.x;
    int v = t >> 4, o = t & 15;
    if (v >= N) return;
    float dacc = 0.f, racc = 0.f;
#pragma unroll
    for (int i = 0; i < 8; ++i) {
        float xv = x[v * 8 + i];
        dacc += xv * b_e1b[i * 16 + o];
        racc += xv * root1[i * 16 + o];
    }
    d1[v * 16 + o] = dacc;
    r1[v * 16 + o] = racc + bias1[o];
}

// Edge kernel layer 1: 16 edges/wave-tile, K=128 via 4x mfma_16x16x32_bf16.
__global__ void edge_l1(const float* __restrict__ x,
                        const float* __restrict__ ea,
                        const int*   __restrict__ eidx,
                        const float* __restrict__ W_e1a, const float* __restrict__ b_e1a,
                        const float* __restrict__ W_e1b,
                        const float* __restrict__ d1,
                        float* __restrict__ agg, int* __restrict__ cnt,
                        int E, int ntiles)
{
    const int lane = threadIdx.x & 63;
    const int m = lane & 15;          // A row (edge in tile) / C col (out chan)
    const int q = lane >> 4;          // quad
    const int wave   = blockIdx.x * (blockDim.x >> 6) + (threadIdx.x >> 6);
    const int nwaves = gridDim.x * (blockDim.x >> 6);

    // B fragments, loaded once: B[k][n] = W_e1b[(i*16+n)*16 + j], j=c*4+q, i=t
    bf16x8 bfrag[4];
#pragma unroll
    for (int c = 0; c < 4; ++c)
#pragma unroll
        for (int t = 0; t < 8; ++t)
            bfrag[c][t] = (bf16)W_e1b[(t * 16 + m) * 16 + (c * 4 + q)];

    for (int tile = wave; tile < ntiles; tile += nwaves) {
        int e = tile * 16 + m;
        int s = eidx[e];
        int d = eidx[E + e];
        float t_ea = ea[e];

        float he[4];
#pragma unroll
        for (int c = 0; c < 4; ++c) {
            int j = c * 4 + q;
            float h = W_e1a[j] * t_ea + b_e1a[j];
            he[c] = h > 0.f ? h : 0.f;
        }

        const float4* xp = (const float4*)(x + (size_t)s * 8);
        float4 x0 = xp[0], x1 = xp[1];
        float xv[8] = {x0.x, x0.y, x0.z, x0.w, x1.x, x1.y, x1.z, x1.w};

        f32x4 acc = {0.f, 0.f, 0.f, 0.f};
#pragma unroll
        for (int c = 0; c < 4; ++c) {
            bf16x8 afrag;
#pragma unroll
            for (int t = 0; t < 8; ++t) afrag[t] = (bf16)(he[c] * xv[t]);
            acc = __builtin_amdgcn_mfma_f32_16x16x32_bf16(afrag, bfrag[c], acc, 0, 0, 0);
        }

        if (q == 0) atomicAdd(&cnt[d], 1);   // count each edge once

        // C layout: lane holds rows r=q*4+reg (edges), col o=lane&15
#pragma unroll
        for (int reg = 0; reg < 4; ++reg) {
            int r   = q * 4 + reg;
            int s_r = __shfl(s, r, 64);
            int d_r = __shfl(d, r, 64);
            float val = acc[reg] + d1[s_r * 16 + m];
            atomicAdd(&agg[d_r * 16 + m], val);
        }
    }
}

// Finalize layer 1 + per-node precompute for layer 2.
__global__ void node_fin1(const float* __restrict__ agg, const int* __restrict__ cnt,
                          const float* __restrict__ r1,
                          const float* __restrict__ b_e2b, const float* __restrict__ root2,
                          const float* __restrict__ bias2,
                          float* __restrict__ h1, float* __restrict__ d2,
                          float* __restrict__ r2, int N)
{
    int t = blockIdx.x * blockDim.x + threadIdx.x;
    int v = t >> 4, o = t & 15;
    if (v >= N) return;
    float c = (float)cnt[v]; c = c > 1.f ? c : 1.f;
    float h = agg[v * 16 + o] / c + r1[v * 16 + o];
    h = h > 0.f ? h : 0.f;
    h1[v * 16 + o] = h;
    float dacc = 0.f, racc = 0.f;
#pragma unroll
    for (int i = 0; i < 16; ++i) {
        float hv = __shfl(h, i, 16);   // h1[v][i] from lane i of the 16-group
        dacc += hv * b_e2b[i * 16 + o];
        racc += hv * root2[i * 16 + o];
    }
    d2[v * 16 + o] = dacc;
    r2[v * 16 + o] = racc + bias2[o];
}

// Edge kernel layer 2: K=256 via 8x mfma_16x16x32_bf16.
__global__ void edge_l2(const float* __restrict__ h1g,
                        const float* __restrict__ ea,
                        const int*   __restrict__ eidx,
                        const float* __restrict__ W_e2a, const float* __restrict__ b_e2a,
                        const float* __restrict__ W_e2b,
                        const float* __restrict__ d2,
                        float* __restrict__ agg, int E, int ntiles)
{
    const int lane = threadIdx.x & 63;
    const int m = lane & 15;
    const int q = lane >> 4;
    const int qh = q >> 1;            // j = 2c + qh
    const int ql = q & 1;             // i = ql*8 + t
    const int wave   = blockIdx.x * (blockDim.x >> 6) + (threadIdx.x >> 6);
    const int nwaves = gridDim.x * (blockDim.x >> 6);

    bf16x8 bfrag[8];
#pragma unroll
    for (int c = 0; c < 8; ++c) {
        int j = c * 2 + qh;
#pragma unroll
        for (int t = 0; t < 8; ++t) {
            int i = ql * 8 + t;
            bfrag[c][t] = (bf16)W_e2b[(i * 16 + m) * 16 + j];
        }
    }

    for (int tile = wave; tile < ntiles; tile += nwaves) {
        int e = tile * 16 + m;
        int s = eidx[e];
        int d = eidx[E + e];
        float t_ea = ea[e];

        float he[8];
#pragma unroll
        for (int c = 0; c < 8; ++c) {
            int j = c * 2 + qh;
            float h = W_e2a[j] * t_ea + b_e2a[j];
            he[c] = h > 0.f ? h : 0.f;
        }

        const float4* hp = (const float4*)(h1g + (size_t)s * 16 + ql * 8);
        float4 h0 = hp[0], h1v = hp[1];
        float hv[8] = {h0.x, h0.y, h0.z, h0.w, h1v.x, h1v.y, h1v.z, h1v.w};

        f32x4 acc = {0.f, 0.f, 0.f, 0.f};
#pragma unroll
        for (int c = 0; c < 8; ++c) {
            bf16x8 afrag;
#pragma unroll
            for (int t = 0; t < 8; ++t) afrag[t] = (bf16)(he[c] * hv[t]);
            acc = __builtin_amdgcn_mfma_f32_16x16x32_bf16(afrag, bfrag[c], acc, 0, 0, 0);
        }

#pragma unroll
        for (int reg = 0; reg < 4; ++reg) {
            int r   = q * 4 + reg;
            int s_r = __shfl(s, r, 64);
            int d_r = __shfl(d, r, 64);
            float val = acc[reg] + d2[s_r * 16 + m];
            atomicAdd(&agg[d_r * 16 + m], val);
        }
    }
}

// Finalize layer 2: write h, accumulate graph pool.
__global__ void node_fin2(const float* __restrict__ agg, const int* __restrict__ cnt,
                          const float* __restrict__ r2, const int* __restrict__ batch,
                          float* __restrict__ out_h, float* __restrict__ gsum,
                          int* __restrict__ gcnt, int N)
{
    int t = blockIdx.x * blockDim.x + threadIdx.x;
    int v = t >> 4, o = t & 15;
    if (v >= N) return;
    float c = (float)cnt[v]; c = c > 1.f ? c : 1.f;
    float h = agg[v * 16 + o] / c + r2[v * 16 + o];
    h = h > 0.f ? h : 0.f;
    out_h[v * 16 + o] = h;
    int b = batch[v];
    atomicAdd(&gsum[b * 16 + o], h);
    if (o == 0) atomicAdd(&gcnt[b], 1);
}

// Pool mean + batch passthrough (as float, per harness flat-f32 output).
__global__ void pool_fin(const float* __restrict__ gsum, const int* __restrict__ gcnt,
                         const int* __restrict__ batch,
                         float* __restrict__ out_g, float* __restrict__ out_b,
                         int B, int N)
{
    int t = blockIdx.x * blockDim.x + threadIdx.x;
    if (t < B * 16) {
        int b = t >> 4;
        float c = (float)gcnt[b]; c = c > 1.f ? c : 1.f;
        out_g[t] = gsum[t] / c;
    }
    if (t < N) out_b[t] = (float)batch[t];
}

extern "C" void kernel_launch(void* const* d_in, const int* in_sizes, int n_in,
                              void* d_out, int out_size, void* d_ws, size_t ws_size,
                              hipStream_t stream)
{
    const float* x     = (const float*)d_in[0];
    const float* ea    = (const float*)d_in[1];
    const float* W_e1a = (const float*)d_in[2];
    const float* b_e1a = (const float*)d_in[3];
    const float* W_e1b = (const float*)d_in[4];
    const float* b_e1b = (const float*)d_in[5];
    const float* root1 = (const float*)d_in[6];
    const float* bias1 = (const float*)d_in[7];
    const float* W_e2a = (const float*)d_in[8];
    const float* b_e2a = (const float*)d_in[9];
    const float* W_e2b = (const float*)d_in[10];
    const float* b_e2b = (const float*)d_in[11];
    const float* root2 = (const float*)d_in[12];
    const float* bias2 = (const float*)d_in[13];
    const int*   eidx  = (const int*)d_in[14];
    const int*   batch = (const int*)d_in[15];

    const int E  = in_sizes[1];       // 800000
    const int N  = in_sizes[15];      // 50000
    const int Bg = (out_size - N * 16 - N) / 16;   // 64

    char* ws = (char*)d_ws;
    size_t off = 0;
    int*   cnt  = (int*)(ws + off);   off += (size_t)N * 4;
    float* agg1 = (float*)(ws + off); off += (size_t)N * 16 * 4;
    float* agg2 = (float*)(ws + off); off += (size_t)N * 16 * 4;
    float* gsum = (float*)(ws + off); off += (size_t)Bg * 16 * 4;
    int*   gcnt = (int*)(ws + off);   off += (size_t)Bg * 4;
    size_t zero_bytes = off;
    float* h1 = (float*)(ws + off); off += (size_t)N * 16 * 4;
    float* d1 = (float*)(ws + off); off += (size_t)N * 16 * 4;
    float* r1 = (float*)(ws + off); off += (size_t)N * 16 * 4;
    float* d2 = (float*)(ws + off); off += (size_t)N * 16 * 4;
    float* r2 = (float*)(ws + off); off += (size_t)N * 16 * 4;

    hipMemsetAsync(d_ws, 0, zero_bytes, stream);

    int nodeBlocks = (N * 16 + 255) / 256;
    int ntiles = E / 16;

    node_pre1<<<nodeBlocks, 256, 0, stream>>>(x, b_e1b, root1, bias1, d1, r1, N);
    edge_l1<<<1024, 256, 0, stream>>>(x, ea, eidx, W_e1a, b_e1a, W_e1b, d1,
                                      agg1, cnt, E, ntiles);
    node_fin1<<<nodeBlocks, 256, 0, stream>>>(agg1, cnt, r1, b_e2b, root2, bias2,
                                              h1, d2, r2, N);
    edge_l2<<<1024, 256, 0, stream>>>(h1, ea, eidx, W_e2a, b_e2a, W_e2b, d2,
                                      agg2, E, ntiles);

    float* out_h = (float*)d_out;
    float* out_g = out_h + (size_t)N * 16;
    float* out_b = out_g + (size_t)Bg * 16;
    node_fin2<<<nodeBlocks, 256, 0, stream>>>(agg2, cnt, r2, batch, out_h,
                                              gsum, gcnt, N);
    int pfThreads = (N > Bg * 16 ? N : Bg * 16);
    pool_fin<<<(pfThreads + 255) / 256, 256, 0, stream>>>(gsum, gcnt, batch,
                                                          out_g, out_b, Bg, N);
}

// Round 2
// 284.225 us; speedup vs baseline: 1.8926x; 1.8926x over previous
//
#include <hip/hip_runtime.h>
#include <hip/hip_bf16.h>

typedef __bf16 bf16;
typedef __bf16 bf16x8 __attribute__((ext_vector_type(8)));
typedef float  f32x4  __attribute__((ext_vector_type(4)));

// ---------------------------------------------------------------------------
// NNConv restructure:
//   msg[e] = Z[e] @ W'  + d[src]   where Z[e][(j,i)] = he[e][j]*x[src][i]
//   (shared-weight GEMM, K=128 (L1) / 256 (L2), 16 edges per wave-tile MFMA)
// Pooling: batch is SORTED -> per-graph contiguous ranges; one block per
// graph does a binary-search + LDS segment reduction (no atomics).
// ---------------------------------------------------------------------------

__global__ void node_pre1(const float* __restrict__ x,
                          const float* __restrict__ b_e1b,
                          const float* __restrict__ root1,
                          const float* __restrict__ bias1,
                          float* __restrict__ d1, float* __restrict__ r1, int N)
{
    int t = blockIdx.x * blockDim.x + threadIdx.x;
    int v = t >> 4, o = t & 15;
    if (v >= N) return;
    float dacc = 0.f, racc = 0.f;
#pragma unroll
    for (int i = 0; i < 8; ++i) {
        float xv = x[v * 8 + i];
        dacc += xv * b_e1b[i * 16 + o];
        racc += xv * root1[i * 16 + o];
    }
    d1[v * 16 + o] = dacc;
    r1[v * 16 + o] = racc + bias1[o];
}

// Edge kernel layer 1: 16 edges/wave-tile, K=128 via 4x mfma_16x16x32_bf16.
__global__ void edge_l1(const float* __restrict__ x,
                        const float* __restrict__ ea,
                        const int*   __restrict__ eidx,
                        const float* __restrict__ W_e1a, const float* __restrict__ b_e1a,
                        const float* __restrict__ W_e1b,
                        const float* __restrict__ d1,
                        float* __restrict__ agg, int* __restrict__ cnt,
                        int E, int ntiles)
{
    const int lane = threadIdx.x & 63;
    const int m = lane & 15;          // A row (edge in tile) / C col (out chan)
    const int q = lane >> 4;          // quad
    const int wave   = blockIdx.x * (blockDim.x >> 6) + (threadIdx.x >> 6);
    const int nwaves = gridDim.x * (blockDim.x >> 6);

    // B fragments, loaded once: B[k][n] = W_e1b[(i*16+n)*16 + j], j=c*4+q, i=t
    bf16x8 bfrag[4];
#pragma unroll
    for (int c = 0; c < 4; ++c)
#pragma unroll
        for (int t = 0; t < 8; ++t)
            bfrag[c][t] = (bf16)W_e1b[(t * 16 + m) * 16 + (c * 4 + q)];

    for (int tile = wave; tile < ntiles; tile += nwaves) {
        int e = tile * 16 + m;
        int s = eidx[e];
        int d = eidx[E + e];
        float t_ea = ea[e];

        float he[4];
#pragma unroll
        for (int c = 0; c < 4; ++c) {
            int j = c * 4 + q;
            float h = W_e1a[j] * t_ea + b_e1a[j];
            he[c] = h > 0.f ? h : 0.f;
        }

        const float4* xp = (const float4*)(x + (size_t)s * 8);
        float4 x0 = xp[0], x1 = xp[1];
        float xv[8] = {x0.x, x0.y, x0.z, x0.w, x1.x, x1.y, x1.z, x1.w};

        f32x4 acc = {0.f, 0.f, 0.f, 0.f};
#pragma unroll
        for (int c = 0; c < 4; ++c) {
            bf16x8 afrag;
#pragma unroll
            for (int t = 0; t < 8; ++t) afrag[t] = (bf16)(he[c] * xv[t]);
            acc = __builtin_amdgcn_mfma_f32_16x16x32_bf16(afrag, bfrag[c], acc, 0, 0, 0);
        }

        if (q == 0) atomicAdd(&cnt[d], 1);   // count each edge once

        // C layout: lane holds rows r=q*4+reg (edges), col o=lane&15
#pragma unroll
        for (int reg = 0; reg < 4; ++reg) {
            int r   = q * 4 + reg;
            int s_r = __shfl(s, r, 64);
            int d_r = __shfl(d, r, 64);
            float val = acc[reg] + d1[s_r * 16 + m];
            atomicAdd(&agg[d_r * 16 + m], val);
        }
    }
}

// Finalize layer 1 + per-node precompute for layer 2.
__global__ void node_fin1(const float* __restrict__ agg, const int* __restrict__ cnt,
                          const float* __restrict__ r1,
                          const float* __restrict__ b_e2b, const float* __restrict__ root2,
                          const float* __restrict__ bias2,
                          float* __restrict__ h1, float* __restrict__ d2,
                          float* __restrict__ r2, int N)
{
    int t = blockIdx.x * blockDim.x + threadIdx.x;
    int v = t >> 4, o = t & 15;
    if (v >= N) return;
    float c = (float)cnt[v]; c = c > 1.f ? c : 1.f;
    float h = agg[v * 16 + o] / c + r1[v * 16 + o];
    h = h > 0.f ? h : 0.f;
    h1[v * 16 + o] = h;
    float dacc = 0.f, racc = 0.f;
#pragma unroll
    for (int i = 0; i < 16; ++i) {
        float hv = __shfl(h, i, 16);   // h1[v][i] from lane i of the 16-group
        dacc += hv * b_e2b[i * 16 + o];
        racc += hv * root2[i * 16 + o];
    }
    d2[v * 16 + o] = dacc;
    r2[v * 16 + o] = racc + bias2[o];
}

// Edge kernel layer 2: K=256 via 8x mfma_16x16x32_bf16.
__global__ void edge_l2(const float* __restrict__ h1g,
                        const float* __restrict__ ea,
                        const int*   __restrict__ eidx,
                        const float* __restrict__ W_e2a, const float* __restrict__ b_e2a,
                        const float* __restrict__ W_e2b,
                        const float* __restrict__ d2,
                        float* __restrict__ agg, int E, int ntiles)
{
    const int lane = threadIdx.x & 63;
    const int m = lane & 15;
    const int q = lane >> 4;
    const int qh = q >> 1;            // j = 2c + qh
    const int ql = q & 1;             // i = ql*8 + t
    const int wave   = blockIdx.x * (blockDim.x >> 6) + (threadIdx.x >> 6);
    const int nwaves = gridDim.x * (blockDim.x >> 6);

    bf16x8 bfrag[8];
#pragma unroll
    for (int c = 0; c < 8; ++c) {
        int j = c * 2 + qh;
#pragma unroll
        for (int t = 0; t < 8; ++t) {
            int i = ql * 8 + t;
            bfrag[c][t] = (bf16)W_e2b[(i * 16 + m) * 16 + j];
        }
    }

    for (int tile = wave; tile < ntiles; tile += nwaves) {
        int e = tile * 16 + m;
        int s = eidx[e];
        int d = eidx[E + e];
        float t_ea = ea[e];

        float he[8];
#pragma unroll
        for (int c = 0; c < 8; ++c) {
            int j = c * 2 + qh;
            float h = W_e2a[j] * t_ea + b_e2a[j];
            he[c] = h > 0.f ? h : 0.f;
        }

        const float4* hp = (const float4*)(h1g + (size_t)s * 16 + ql * 8);
        float4 h0 = hp[0], h1v = hp[1];
        float hv[8] = {h0.x, h0.y, h0.z, h0.w, h1v.x, h1v.y, h1v.z, h1v.w};

        f32x4 acc = {0.f, 0.f, 0.f, 0.f};
#pragma unroll
        for (int c = 0; c < 8; ++c) {
            bf16x8 afrag;
#pragma unroll
            for (int t = 0; t < 8; ++t) afrag[t] = (bf16)(he[c] * hv[t]);
            acc = __builtin_amdgcn_mfma_f32_16x16x32_bf16(afrag, bfrag[c], acc, 0, 0, 0);
        }

#pragma unroll
        for (int reg = 0; reg < 4; ++reg) {
            int r   = q * 4 + reg;
            int s_r = __shfl(s, r, 64);
            int d_r = __shfl(d, r, 64);
            float val = acc[reg] + d2[s_r * 16 + m];
            atomicAdd(&agg[d_r * 16 + m], val);
        }
    }
}

// Finalize layer 2: pure streaming elementwise (NO pooling atomics here).
__global__ void node_fin2(const float* __restrict__ agg, const int* __restrict__ cnt,
                          const float* __restrict__ r2, const int* __restrict__ batch,
                          float* __restrict__ out_h, float* __restrict__ out_b, int N)
{
    int t = blockIdx.x * blockDim.x + threadIdx.x;
    int v = t >> 4, o = t & 15;
    if (v >= N) return;
    float c = (float)cnt[v]; c = c > 1.f ? c : 1.f;
    float h = agg[v * 16 + o] / c + r2[v * 16 + o];
    h = h > 0.f ? h : 0.f;
    out_h[v * 16 + o] = h;
    if (o == 0) out_b[v] = (float)batch[v];   // batch passthrough as f32
}

// Global mean pool: batch is sorted -> one block per graph, binary-search the
// node range, LDS segment reduction. Zero atomics.
__global__ void pool_seg(const float* __restrict__ h, const int* __restrict__ batch,
                         float* __restrict__ out_g, int N)
{
    const int b = blockIdx.x;
    // lower_bound(batch, b) and lower_bound(batch, b+1)
    int lo = 0, hi = N;
    while (lo < hi) { int mid = (lo + hi) >> 1; if (batch[mid] < b) lo = mid + 1; else hi = mid; }
    const int start = lo;
    hi = N;
    while (lo < hi) { int mid = (lo + hi) >> 1; if (batch[mid] < b + 1) lo = mid + 1; else hi = mid; }
    const int end = lo;

    const int ch = threadIdx.x & 15, grp = threadIdx.x >> 4;   // 16 node-groups
    float acc = 0.f;
    for (int v = start + grp; v < end; v += 16)
        acc += h[(size_t)v * 16 + ch];

    __shared__ float red[256];
    red[threadIdx.x] = acc;
    __syncthreads();
#pragma unroll
    for (int s = 128; s >= 16; s >>= 1) {
        if (threadIdx.x < s) red[threadIdx.x] += red[threadIdx.x + s];
        __syncthreads();
    }
    if (threadIdx.x < 16) {
        float c = (float)(end - start); c = c > 1.f ? c : 1.f;
        out_g[b * 16 + threadIdx.x] = red[threadIdx.x] / c;
    }
}

extern "C" void kernel_launch(void* const* d_in, const int* in_sizes, int n_in,
                              void* d_out, int out_size, void* d_ws, size_t ws_size,
                              hipStream_t stream)
{
    const float* x     = (const float*)d_in[0];
    const float* ea    = (const float*)d_in[1];
    const float* W_e1a = (const float*)d_in[2];
    const float* b_e1a = (const float*)d_in[3];
    const float* W_e1b = (const float*)d_in[4];
    const float* b_e1b = (const float*)d_in[5];
    const float* root1 = (const float*)d_in[6];
    const float* bias1 = (const float*)d_in[7];
    const float* W_e2a = (const float*)d_in[8];
    const float* b_e2a = (const float*)d_in[9];
    const float* W_e2b = (const float*)d_in[10];
    const float* b_e2b = (const float*)d_in[11];
    const float* root2 = (const float*)d_in[12];
    const float* bias2 = (const float*)d_in[13];
    const int*   eidx  = (const int*)d_in[14];
    const int*   batch = (const int*)d_in[15];

    const int E  = in_sizes[1];       // 800000
    const int N  = in_sizes[15];      // 50000
    const int Bg = (out_size - N * 16 - N) / 16;   // 64

    char* ws = (char*)d_ws;
    size_t off = 0;
    int*   cnt  = (int*)(ws + off);   off += (size_t)N * 4;
    float* agg1 = (float*)(ws + off); off += (size_t)N * 16 * 4;
    float* agg2 = (float*)(ws + off); off += (size_t)N * 16 * 4;
    size_t zero_bytes = off;
    float* h1 = (float*)(ws + off); off += (size_t)N * 16 * 4;
    float* d1 = (float*)(ws + off); off += (size_t)N * 16 * 4;
    float* r1 = (float*)(ws + off); off += (size_t)N * 16 * 4;
    float* d2 = (float*)(ws + off); off += (size_t)N * 16 * 4;
    float* r2 = (float*)(ws + off); off += (size_t)N * 16 * 4;

    hipMemsetAsync(d_ws, 0, zero_bytes, stream);

    int nodeBlocks = (N * 16 + 255) / 256;
    int ntiles = E / 16;

    node_pre1<<<nodeBlocks, 256, 0, stream>>>(x, b_e1b, root1, bias1, d1, r1, N);
    edge_l1<<<1024, 256, 0, stream>>>(x, ea, eidx, W_e1a, b_e1a, W_e1b, d1,
                                      agg1, cnt, E, ntiles);
    node_fin1<<<nodeBlocks, 256, 0, stream>>>(agg1, cnt, r1, b_e2b, root2, bias2,
                                              h1, d2, r2, N);
    edge_l2<<<1024, 256, 0, stream>>>(h1, ea, eidx, W_e2a, b_e2a, W_e2b, d2,
                                      agg2, E, ntiles);

    float* out_h = (float*)d_out;
    float* out_g = out_h + (size_t)N * 16;
    float* out_b = out_g + (size_t)Bg * 16;
    node_fin2<<<nodeBlocks, 256, 0, stream>>>(agg2, cnt, r2, batch, out_h,
                                              out_b, N);
    pool_seg<<<Bg, 256, 0, stream>>>(out_h, batch, out_g, N);
}